// Round 1
// baseline (565.895 us; speedup 1.0000x reference)
//
#include <hip/hip_runtime.h>
#include <math.h>

#define N_NODES 20000
#define N_EDGES 160000
#define NODE_DIM 64
#define EDGE_DIM 16
#define H 32
#define STEPS 3
#define UROW 544   // U[v][c]: c = i*16+d for c<512 (i=c>>4,d=c&15); c=512+i is bias plane

// ---------------------------------------------------------------------------
// CSR build (once per call), done twice: by src (for edge_msg locality) and
// by dst (for the atomic-free gather in the GRU). hist -> 2-level scan ->
// atomic fill. The src fill directly emits sorted src2/dst2/eperm; the dst
// fill emits jlist = positions-in-src-sorted-order grouped by dst.
// ---------------------------------------------------------------------------
__global__ void hist_src_kernel(const int* __restrict__ ei, int* __restrict__ deg) {
    int e = blockIdx.x * 256 + threadIdx.x;
    if (e < N_EDGES) atomicAdd(&deg[ei[e]], 1);               // row 0 = src
}

__global__ void hist_dst_kernel(const int* __restrict__ ei, int* __restrict__ deg) {
    int e = blockIdx.x * 256 + threadIdx.x;
    if (e < N_EDGES) atomicAdd(&deg[ei[N_EDGES + e]], 1);     // row 1 = dst
}

__global__ void scan_a_kernel(const int* __restrict__ deg,
                              int* __restrict__ part, int* __restrict__ bsum) {
    __shared__ int s[256];
    int v = blockIdx.x * 256 + threadIdx.x;
    int x = (v < N_NODES) ? deg[v] : 0;
    s[threadIdx.x] = x;
    __syncthreads();
    for (int off = 1; off < 256; off <<= 1) {
        int t = (threadIdx.x >= off) ? s[threadIdx.x - off] : 0;
        __syncthreads();
        s[threadIdx.x] += t;
        __syncthreads();
    }
    if (v < N_NODES) part[v] = s[threadIdx.x] - x;
    if (threadIdx.x == 255) bsum[blockIdx.x] = s[255];
}

__global__ void scan_b_kernel(int* __restrict__ rowptr,
                              const int* __restrict__ bsum,
                              int* __restrict__ cursor) {
    __shared__ int boff[80];
    if (threadIdx.x == 0) {
        int run = 0;
        for (int b = 0; b < 79; ++b) { boff[b] = run; run += bsum[b]; }
    }
    __syncthreads();
    for (int v = threadIdx.x; v < N_NODES; v += 256) {
        int r = rowptr[v] + boff[v >> 8];
        rowptr[v] = r;
        cursor[v] = r;
    }
    if (threadIdx.x == 0) rowptr[N_NODES] = N_EDGES;
}

__global__ void fill_src_kernel(const int* __restrict__ ei, int* __restrict__ cursor,
                                int* __restrict__ eperm, int* __restrict__ src2,
                                int* __restrict__ dst2) {
    int e = blockIdx.x * 256 + threadIdx.x;
    if (e < N_EDGES) {
        int s = ei[e];
        int slot = atomicAdd(&cursor[s], 1);
        eperm[slot] = e;
        src2[slot]  = s;
        dst2[slot]  = ei[N_EDGES + e];
    }
}

// groups src-sorted edge positions j by their dst node
__global__ void fill_dst_kernel(const int* __restrict__ dst2, int* __restrict__ cursor,
                                int* __restrict__ jlist) {
    int j = blockIdx.x * 256 + threadIdx.x;
    if (j < N_EDGES) {
        int slot = atomicAdd(&cursor[dst2[j]], 1);
        jlist[slot] = j;
    }
}

__global__ void permute_ef_kernel(const float* __restrict__ ef,
                                  const int* __restrict__ eperm,
                                  float* __restrict__ ef2) {
    int t = blockIdx.x * 256 + threadIdx.x;
    if (t < N_EDGES * EDGE_DIM) {
        int j = t >> 4;
        int d = t & 15;
        ef2[t] = ef[eperm[j] * EDGE_DIM + d];
    }
}

// ---------------------------------------------------------------------------
// node projection: h = node_feat @ W_np.T + b_np
// ---------------------------------------------------------------------------
__global__ void node_proj_kernel(const float* __restrict__ nf,
                                 const float* __restrict__ W,
                                 const float* __restrict__ b,
                                 float* __restrict__ h) {
    int tid = blockIdx.x * blockDim.x + threadIdx.x;
    if (tid >= N_NODES * H) return;
    int v = tid >> 5;
    int i = tid & 31;
    const float* __restrict__ row = nf + v * NODE_DIM;
    const float* __restrict__ w   = W + i * NODE_DIM;
    float acc = b[i];
#pragma unroll
    for (int d = 0; d < NODE_DIM; ++d) acc = fmaf(row[d], w[d], acc);
    h[tid] = acc;
}

// ---------------------------------------------------------------------------
// U precompute v3: U[v, c] = sum_k Wx[k][c] * h[v,k]
// where Wx[k][c] = We[((c>>4)*32+k)*16 + (c&15)]  (c < 512)
//                = be[(c-512)*32 + k]             (512 <= c < 544, bias plane)
// 576 threads/block, thread t owns column c=t (32 W regs); h rows staged in
// 4 KB LDS, read as pure same-address broadcast float4. 2 nodes/iter.
// ---------------------------------------------------------------------------
__global__ __launch_bounds__(576)
void u_precompute_kernel(const float* __restrict__ We,
                         const float* __restrict__ be,
                         const float* __restrict__ h,
                         float* __restrict__ U) {
    __shared__ float hs[32 * 32];   // 4 KB
    int t = threadIdx.x;
    int c = t;

    float wreg[32];
    if (c < 512) {
        int i = c >> 4, d = c & 15;
#pragma unroll
        for (int k = 0; k < H; ++k) wreg[k] = We[(i * H + k) * EDGE_DIM + d];
    } else if (c < UROW) {
        int i = c - 512;
#pragma unroll
        for (int k = 0; k < H; ++k) wreg[k] = be[i * H + k];
    }

    for (int v0 = blockIdx.x * 32; v0 < N_NODES; v0 += gridDim.x * 32) {
        __syncthreads();
        for (int idx = t; idx < 32 * 32; idx += 576) hs[idx] = h[v0 * H + idx];
        __syncthreads();

        for (int n = 0; n < 32; n += 2) {
            const float4* __restrict__ hp0 = (const float4*)(hs + n * H);
            const float4* __restrict__ hp1 = (const float4*)(hs + (n + 1) * H);
            float a0 = 0.f, a1 = 0.f;
#pragma unroll
            for (int kk = 0; kk < 8; ++kk) {
                float4 q0 = hp0[kk];
                float4 q1 = hp1[kk];
                a0 = fmaf(wreg[4 * kk + 0], q0.x, a0);
                a1 = fmaf(wreg[4 * kk + 0], q1.x, a1);
                a0 = fmaf(wreg[4 * kk + 1], q0.y, a0);
                a1 = fmaf(wreg[4 * kk + 1], q1.y, a1);
                a0 = fmaf(wreg[4 * kk + 2], q0.z, a0);
                a1 = fmaf(wreg[4 * kk + 2], q1.z, a1);
                a0 = fmaf(wreg[4 * kk + 3], q0.w, a0);
                a1 = fmaf(wreg[4 * kk + 3], q1.w, a1);
            }
            if (c < UROW) {
                U[(size_t)(v0 + n)     * UROW + c] = a0;
                U[(size_t)(v0 + n + 1) * UROW + c] = a1;
            }
        }
    }
}

// ---------------------------------------------------------------------------
// Edge message (src-sorted, edge-parallel, STREAMING store — no atomics):
//   msg[j,i] = U[s,512+i] + sum_d ef2[j,d] * U[s, i*16+d]
// Consecutive half-waves share src rows (sorted) -> L1/L2 reuse of U.
// The dst scatter is deferred to the GRU's dst-CSR gather.
// ---------------------------------------------------------------------------
__global__ __launch_bounds__(256)
void edge_msg_kernel(const int* __restrict__ src2,
                     const float* __restrict__ ef2,
                     const float* __restrict__ U,
                     float* __restrict__ msg_out) {
    int tid  = blockIdx.x * blockDim.x + threadIdx.x;
    int j    = tid >> 5;
    int lane = tid & 31;
    if (j >= N_EDGES) return;

    int s = src2[j];

    float efv = (lane < EDGE_DIM) ? ef2[j * EDGE_DIM + lane] : 0.f;

    const float* __restrict__ Up = U + (size_t)s * UROW;
    const float4* __restrict__ Urow = (const float4*)(Up + lane * EDGE_DIM);
    float4 u0 = Urow[0];
    float4 u1 = Urow[1];
    float4 u2 = Urow[2];
    float4 u3 = Urow[3];

    float msg = Up[512 + lane];   // bias plane
    msg = fmaf(__shfl(efv,  0, 32), u0.x, msg);
    msg = fmaf(__shfl(efv,  1, 32), u0.y, msg);
    msg = fmaf(__shfl(efv,  2, 32), u0.z, msg);
    msg = fmaf(__shfl(efv,  3, 32), u0.w, msg);
    msg = fmaf(__shfl(efv,  4, 32), u1.x, msg);
    msg = fmaf(__shfl(efv,  5, 32), u1.y, msg);
    msg = fmaf(__shfl(efv,  6, 32), u1.z, msg);
    msg = fmaf(__shfl(efv,  7, 32), u1.w, msg);
    msg = fmaf(__shfl(efv,  8, 32), u2.x, msg);
    msg = fmaf(__shfl(efv,  9, 32), u2.y, msg);
    msg = fmaf(__shfl(efv, 10, 32), u2.z, msg);
    msg = fmaf(__shfl(efv, 11, 32), u2.w, msg);
    msg = fmaf(__shfl(efv, 12, 32), u3.x, msg);
    msg = fmaf(__shfl(efv, 13, 32), u3.y, msg);
    msg = fmaf(__shfl(efv, 14, 32), u3.z, msg);
    msg = fmaf(__shfl(efv, 15, 32), u3.w, msg);

    msg_out[(size_t)j * H + lane] = msg;   // coalesced 128B per half-wave
}

// ---------------------------------------------------------------------------
// GRU cell + fused dst-CSR gather of messages (replaces atomic scatter).
// LDS staging stride padded 96 -> 97: write addr = k*97+row has banks
// (k+row)%32, conflict-free (was 32-way: k*96 ≡ 0 mod 32 banks).
// ---------------------------------------------------------------------------
__global__ __launch_bounds__(256)
void gru_kernel(const float* __restrict__ Wih,
                const float* __restrict__ Whh,
                const float* __restrict__ bih,
                const float* __restrict__ bhh,
                const float* __restrict__ msg,
                const int* __restrict__ rowptr_d,
                const int* __restrict__ jlist,
                const float* __restrict__ h,
                float* __restrict__ hout) {
    __shared__ float WihT[H * 97];   // [k][row], stride 97 (pad kills bank conflict)
    __shared__ float WhhT[H * 97];
    for (int idx = threadIdx.x; idx < 3 * H * H; idx += 256) {
        int row = idx >> 5;
        int k   = idx & 31;
        WihT[k * 97 + row] = Wih[idx];
        WhhT[k * 97 + row] = Whh[idx];
    }
    __syncthreads();

    int lane = threadIdx.x & 31;
    int grp  = threadIdx.x >> 5;

    for (int v0 = blockIdx.x * 8; v0 < N_NODES; v0 += gridDim.x * 8) {
        int v = v0 + grp;
        if (v < N_NODES) {
            // gather incoming messages (dst-CSR) — avg 8 coalesced 128B loads
            int beg = rowptr_d[v];
            int end = rowptr_d[v + 1];
            float mv = 0.f;
            for (int p = beg; p < end; ++p) {
                int j = jlist[p];
                mv += msg[(size_t)j * H + lane];
            }

            float hv = h[v * H + lane];
            float ir = bih[lane], iz = bih[H + lane], in_ = bih[2 * H + lane];
            float hr = bhh[lane], hz = bhh[H + lane], hn  = bhh[2 * H + lane];
#pragma unroll
            for (int k = 0; k < H; ++k) {
                float mk = __shfl(mv, k, 32);
                float hk = __shfl(hv, k, 32);
                ir  = fmaf(WihT[k * 97 + lane],          mk, ir);
                iz  = fmaf(WihT[k * 97 + H + lane],      mk, iz);
                in_ = fmaf(WihT[k * 97 + 2 * H + lane],  mk, in_);
                hr  = fmaf(WhhT[k * 97 + lane],          hk, hr);
                hz  = fmaf(WhhT[k * 97 + H + lane],      hk, hz);
                hn  = fmaf(WhhT[k * 97 + 2 * H + lane],  hk, hn);
            }
            float r  = 1.f / (1.f + __expf(-(ir + hr)));
            float z  = 1.f / (1.f + __expf(-(iz + hz)));
            float nn = tanhf(in_ + r * hn);
            hout[v * H + lane] = (1.f - z) * nn + z * hv;
        }
    }
}

// ---------------------------------------------------------------------------
extern "C" void kernel_launch(void* const* d_in, const int* in_sizes, int n_in,
                              void* d_out, int out_size, void* d_ws, size_t ws_size,
                              hipStream_t stream) {
    const float* node_feat = (const float*)d_in[0];
    const int*   edge_idx  = (const int*)  d_in[1];
    const float* edge_feat = (const float*)d_in[2];
    const float* W_np      = (const float*)d_in[3];
    const float* b_np      = (const float*)d_in[4];
    const float* W_e       = (const float*)d_in[5];
    const float* b_e       = (const float*)d_in[6];
    const float* W_ih      = (const float*)d_in[7];
    const float* W_hh      = (const float*)d_in[8];
    const float* b_ih      = (const float*)d_in[9];
    const float* b_hh      = (const float*)d_in[10];

    float* h      = (float*)d_ws;                             // N*H
    float* U      = h + (size_t)N_NODES * H;                  // N*UROW
    float* ef2    = U + (size_t)N_NODES * UROW;               // E*EDGE_DIM
    float* msg    = ef2 + (size_t)N_EDGES * EDGE_DIM;         // E*H (20.5 MB)
    int* rowptr   = (int*)(msg + (size_t)N_EDGES * H);        // N+1
    int* cursor   = rowptr + (N_NODES + 1);                   // N
    int* bsum     = cursor + N_NODES;                         // 80
    int* rowptr_d = bsum + 80;                                // N+1
    int* cursor_d = rowptr_d + (N_NODES + 1);                 // N
    int* bsum_d   = cursor_d + N_NODES;                       // 80
    int* eperm    = bsum_d + 80;                              // E
    int* src2     = eperm + N_EDGES;                          // E
    int* dst2     = src2 + N_EDGES;                           // E
    int* jlist    = dst2 + N_EDGES;                           // E
    float* out    = (float*)d_out;

    // ---- one-time: build src-sorted edge arrays + dst-CSR gather lists ----
    hipMemsetAsync(cursor,   0, N_NODES * sizeof(int), stream);
    hipMemsetAsync(cursor_d, 0, N_NODES * sizeof(int), stream);
    hist_src_kernel<<<(N_EDGES + 255) / 256, 256, 0, stream>>>(edge_idx, cursor);
    hist_dst_kernel<<<(N_EDGES + 255) / 256, 256, 0, stream>>>(edge_idx, cursor_d);
    scan_a_kernel<<<(N_NODES + 255) / 256, 256, 0, stream>>>(cursor, rowptr, bsum);
    scan_b_kernel<<<1, 256, 0, stream>>>(rowptr, bsum, cursor);
    scan_a_kernel<<<(N_NODES + 255) / 256, 256, 0, stream>>>(cursor_d, rowptr_d, bsum_d);
    scan_b_kernel<<<1, 256, 0, stream>>>(rowptr_d, bsum_d, cursor_d);
    fill_src_kernel<<<(N_EDGES + 255) / 256, 256, 0, stream>>>(edge_idx, cursor,
                                                               eperm, src2, dst2);
    fill_dst_kernel<<<(N_EDGES + 255) / 256, 256, 0, stream>>>(dst2, cursor_d, jlist);
    permute_ef_kernel<<<(N_EDGES * EDGE_DIM + 255) / 256, 256, 0, stream>>>(
        edge_feat, eperm, ef2);

    // ---- h0 ----
    node_proj_kernel<<<(N_NODES * H + 255) / 256, 256, 0, stream>>>(
        node_feat, W_np, b_np, h);

    // ---- 3 propagation steps ----
    for (int step = 0; step < STEPS; ++step) {
        u_precompute_kernel<<<313, 576, 0, stream>>>(W_e, b_e, h, U);
        edge_msg_kernel<<<(N_EDGES * H + 255) / 256, 256, 0, stream>>>(
            src2, ef2, U, msg);
        float* dst_h = (step == STEPS - 1) ? out : h;
        gru_kernel<<<256, 256, 0, stream>>>(W_ih, W_hh, b_ih, b_hh,
                                            msg, rowptr_d, jlist, h, dst_h);
    }
}

// Round 2
// 482.227 us; speedup vs baseline: 1.1735x; 1.1735x over previous
//
#include <hip/hip_runtime.h>
#include <math.h>

#define N_NODES 20000
#define N_EDGES 160000
#define NODE_DIM 64
#define EDGE_DIM 16
#define H 32
#define STEPS 3
#define UROW 544   // U[v][c]: c = i*16+d for c<512 (i=c>>4,d=c&15); c=512+i is bias plane

// ---------------------------------------------------------------------------
// CSR build (once per call), twice: by src (edge_msg U-row locality) and by
// dst (contiguous message rows for the GRU gather). hist -> 2-level scan ->
// atomic fill. The dst fill emits jslot[j] = dst-sorted slot for src-sorted
// edge j, so edge_msg SCATTER-WRITES (latency-tolerant) and the GRU reads
// CONTIGUOUS rows (no indirection, no pointer chase).
// ---------------------------------------------------------------------------
__global__ void hist_src_kernel(const int* __restrict__ ei, int* __restrict__ deg) {
    int e = blockIdx.x * 256 + threadIdx.x;
    if (e < N_EDGES) atomicAdd(&deg[ei[e]], 1);               // row 0 = src
}

__global__ void hist_dst_kernel(const int* __restrict__ ei, int* __restrict__ deg) {
    int e = blockIdx.x * 256 + threadIdx.x;
    if (e < N_EDGES) atomicAdd(&deg[ei[N_EDGES + e]], 1);     // row 1 = dst
}

__global__ void scan_a_kernel(const int* __restrict__ deg,
                              int* __restrict__ part, int* __restrict__ bsum) {
    __shared__ int s[256];
    int v = blockIdx.x * 256 + threadIdx.x;
    int x = (v < N_NODES) ? deg[v] : 0;
    s[threadIdx.x] = x;
    __syncthreads();
    for (int off = 1; off < 256; off <<= 1) {
        int t = (threadIdx.x >= off) ? s[threadIdx.x - off] : 0;
        __syncthreads();
        s[threadIdx.x] += t;
        __syncthreads();
    }
    if (v < N_NODES) part[v] = s[threadIdx.x] - x;
    if (threadIdx.x == 255) bsum[blockIdx.x] = s[255];
}

__global__ void scan_b_kernel(int* __restrict__ rowptr,
                              const int* __restrict__ bsum,
                              int* __restrict__ cursor) {
    __shared__ int boff[80];
    if (threadIdx.x == 0) {
        int run = 0;
        for (int b = 0; b < 79; ++b) { boff[b] = run; run += bsum[b]; }
    }
    __syncthreads();
    for (int v = threadIdx.x; v < N_NODES; v += 256) {
        int r = rowptr[v] + boff[v >> 8];
        rowptr[v] = r;
        cursor[v] = r;
    }
    if (threadIdx.x == 0) rowptr[N_NODES] = N_EDGES;
}

__global__ void fill_src_kernel(const int* __restrict__ ei, int* __restrict__ cursor,
                                int* __restrict__ eperm, int* __restrict__ src2,
                                int* __restrict__ dst2) {
    int e = blockIdx.x * 256 + threadIdx.x;
    if (e < N_EDGES) {
        int s = ei[e];
        int slot = atomicAdd(&cursor[s], 1);
        eperm[slot] = e;
        src2[slot]  = s;
        dst2[slot]  = ei[N_EDGES + e];
    }
}

// jslot[j] = position of src-sorted edge j within the dst-sorted ordering
__global__ void fill_dst_kernel(const int* __restrict__ dst2, int* __restrict__ cursor,
                                int* __restrict__ jslot) {
    int j = blockIdx.x * 256 + threadIdx.x;
    if (j < N_EDGES) {
        int slot = atomicAdd(&cursor[dst2[j]], 1);
        jslot[j] = slot;
    }
}

__global__ void permute_ef_kernel(const float* __restrict__ ef,
                                  const int* __restrict__ eperm,
                                  float* __restrict__ ef2) {
    int t = blockIdx.x * 256 + threadIdx.x;
    if (t < N_EDGES * EDGE_DIM) {
        int j = t >> 4;
        int d = t & 15;
        ef2[t] = ef[eperm[j] * EDGE_DIM + d];
    }
}

// ---------------------------------------------------------------------------
// node projection: h = node_feat @ W_np.T + b_np
// ---------------------------------------------------------------------------
__global__ void node_proj_kernel(const float* __restrict__ nf,
                                 const float* __restrict__ W,
                                 const float* __restrict__ b,
                                 float* __restrict__ h) {
    int tid = blockIdx.x * blockDim.x + threadIdx.x;
    if (tid >= N_NODES * H) return;
    int v = tid >> 5;
    int i = tid & 31;
    const float* __restrict__ row = nf + v * NODE_DIM;
    const float* __restrict__ w   = W + i * NODE_DIM;
    float acc = b[i];
#pragma unroll
    for (int d = 0; d < NODE_DIM; ++d) acc = fmaf(row[d], w[d], acc);
    h[tid] = acc;
}

// ---------------------------------------------------------------------------
// U precompute v3: U[v, c] = sum_k Wx[k][c] * h[v,k]
// where Wx[k][c] = We[((c>>4)*32+k)*16 + (c&15)]  (c < 512)
//                = be[(c-512)*32 + k]             (512 <= c < 544, bias plane)
// ---------------------------------------------------------------------------
__global__ __launch_bounds__(576)
void u_precompute_kernel(const float* __restrict__ We,
                         const float* __restrict__ be,
                         const float* __restrict__ h,
                         float* __restrict__ U) {
    __shared__ float hs[32 * 32];   // 4 KB
    int t = threadIdx.x;
    int c = t;

    float wreg[32];
    if (c < 512) {
        int i = c >> 4, d = c & 15;
#pragma unroll
        for (int k = 0; k < H; ++k) wreg[k] = We[(i * H + k) * EDGE_DIM + d];
    } else if (c < UROW) {
        int i = c - 512;
#pragma unroll
        for (int k = 0; k < H; ++k) wreg[k] = be[i * H + k];
    }

    for (int v0 = blockIdx.x * 32; v0 < N_NODES; v0 += gridDim.x * 32) {
        __syncthreads();
        for (int idx = t; idx < 32 * 32; idx += 576) hs[idx] = h[v0 * H + idx];
        __syncthreads();

        for (int n = 0; n < 32; n += 2) {
            const float4* __restrict__ hp0 = (const float4*)(hs + n * H);
            const float4* __restrict__ hp1 = (const float4*)(hs + (n + 1) * H);
            float a0 = 0.f, a1 = 0.f;
#pragma unroll
            for (int kk = 0; kk < 8; ++kk) {
                float4 q0 = hp0[kk];
                float4 q1 = hp1[kk];
                a0 = fmaf(wreg[4 * kk + 0], q0.x, a0);
                a1 = fmaf(wreg[4 * kk + 0], q1.x, a1);
                a0 = fmaf(wreg[4 * kk + 1], q0.y, a0);
                a1 = fmaf(wreg[4 * kk + 1], q1.y, a1);
                a0 = fmaf(wreg[4 * kk + 2], q0.z, a0);
                a1 = fmaf(wreg[4 * kk + 2], q1.z, a1);
                a0 = fmaf(wreg[4 * kk + 3], q0.w, a0);
                a1 = fmaf(wreg[4 * kk + 3], q1.w, a1);
            }
            if (c < UROW) {
                U[(size_t)(v0 + n)     * UROW + c] = a0;
                U[(size_t)(v0 + n + 1) * UROW + c] = a1;
            }
        }
    }
}

// ---------------------------------------------------------------------------
// Edge message (src-sorted read, dst-sorted SCATTER write — no atomics):
//   msg[jslot[j], i] = U[s,512+i] + sum_d ef2[j,d] * U[s, i*16+d]
// Consecutive half-waves share src rows (sorted) -> L1/L2 reuse of U.
// Scatter store is fire-and-forget; GRU then reads contiguous rows.
// ---------------------------------------------------------------------------
__global__ __launch_bounds__(256)
void edge_msg_kernel(const int* __restrict__ src2,
                     const int* __restrict__ jslot,
                     const float* __restrict__ ef2,
                     const float* __restrict__ U,
                     float* __restrict__ msg_out) {
    int tid  = blockIdx.x * blockDim.x + threadIdx.x;
    int j    = tid >> 5;
    int lane = tid & 31;
    if (j >= N_EDGES) return;

    int s    = src2[j];
    int slot = jslot[j];

    float efv = (lane < EDGE_DIM) ? ef2[j * EDGE_DIM + lane] : 0.f;

    const float* __restrict__ Up = U + (size_t)s * UROW;
    const float4* __restrict__ Urow = (const float4*)(Up + lane * EDGE_DIM);
    float4 u0 = Urow[0];
    float4 u1 = Urow[1];
    float4 u2 = Urow[2];
    float4 u3 = Urow[3];

    float msg = Up[512 + lane];   // bias plane
    msg = fmaf(__shfl(efv,  0, 32), u0.x, msg);
    msg = fmaf(__shfl(efv,  1, 32), u0.y, msg);
    msg = fmaf(__shfl(efv,  2, 32), u0.z, msg);
    msg = fmaf(__shfl(efv,  3, 32), u0.w, msg);
    msg = fmaf(__shfl(efv,  4, 32), u1.x, msg);
    msg = fmaf(__shfl(efv,  5, 32), u1.y, msg);
    msg = fmaf(__shfl(efv,  6, 32), u1.z, msg);
    msg = fmaf(__shfl(efv,  7, 32), u1.w, msg);
    msg = fmaf(__shfl(efv,  8, 32), u2.x, msg);
    msg = fmaf(__shfl(efv,  9, 32), u2.y, msg);
    msg = fmaf(__shfl(efv, 10, 32), u2.z, msg);
    msg = fmaf(__shfl(efv, 11, 32), u2.w, msg);
    msg = fmaf(__shfl(efv, 12, 32), u3.x, msg);
    msg = fmaf(__shfl(efv, 13, 32), u3.y, msg);
    msg = fmaf(__shfl(efv, 14, 32), u3.z, msg);
    msg = fmaf(__shfl(efv, 15, 32), u3.w, msg);

    msg_out[(size_t)slot * H + lane] = msg;   // scatter to dst-sorted slot
}

// ---------------------------------------------------------------------------
// GRU cell + fused CONTIGUOUS gather (msg rows are dst-sorted).
// LDS staging stride 97 -> conflict-free (verified: SQ_LDS_BANK_CONFLICT=0).
// Grid = 2500 blocks (8 nodes/block) for latency hiding.
// ---------------------------------------------------------------------------
__global__ __launch_bounds__(256)
void gru_kernel(const float* __restrict__ Wih,
                const float* __restrict__ Whh,
                const float* __restrict__ bih,
                const float* __restrict__ bhh,
                const float* __restrict__ msg,
                const int* __restrict__ rowptr_d,
                const float* __restrict__ h,
                float* __restrict__ hout) {
    __shared__ float WihT[H * 97];   // [k][row], stride 97 (pad kills bank conflict)
    __shared__ float WhhT[H * 97];
    for (int idx = threadIdx.x; idx < 3 * H * H; idx += 256) {
        int row = idx >> 5;
        int k   = idx & 31;
        WihT[k * 97 + row] = Wih[idx];
        WhhT[k * 97 + row] = Whh[idx];
    }
    __syncthreads();

    int lane = threadIdx.x & 31;
    int grp  = threadIdx.x >> 5;

    for (int v0 = blockIdx.x * 8; v0 < N_NODES; v0 += gridDim.x * 8) {
        int v = v0 + grp;
        if (v < N_NODES) {
            // contiguous gather: rows [beg,end) of dst-sorted msg
            int beg = rowptr_d[v];
            int end = rowptr_d[v + 1];
            float mv = 0.f;
            const float* __restrict__ mp = msg + (size_t)beg * H + lane;
            for (int p = beg; p < end; ++p) {
                mv += *mp;
                mp += H;
            }

            float hv = h[v * H + lane];
            float ir = bih[lane], iz = bih[H + lane], in_ = bih[2 * H + lane];
            float hr = bhh[lane], hz = bhh[H + lane], hn  = bhh[2 * H + lane];
#pragma unroll
            for (int k = 0; k < H; ++k) {
                float mk = __shfl(mv, k, 32);
                float hk = __shfl(hv, k, 32);
                ir  = fmaf(WihT[k * 97 + lane],          mk, ir);
                iz  = fmaf(WihT[k * 97 + H + lane],      mk, iz);
                in_ = fmaf(WihT[k * 97 + 2 * H + lane],  mk, in_);
                hr  = fmaf(WhhT[k * 97 + lane],          hk, hr);
                hz  = fmaf(WhhT[k * 97 + H + lane],      hk, hz);
                hn  = fmaf(WhhT[k * 97 + 2 * H + lane],  hk, hn);
            }
            float r  = 1.f / (1.f + __expf(-(ir + hr)));
            float z  = 1.f / (1.f + __expf(-(iz + hz)));
            float nn = tanhf(in_ + r * hn);
            hout[v * H + lane] = (1.f - z) * nn + z * hv;
        }
    }
}

// ---------------------------------------------------------------------------
extern "C" void kernel_launch(void* const* d_in, const int* in_sizes, int n_in,
                              void* d_out, int out_size, void* d_ws, size_t ws_size,
                              hipStream_t stream) {
    const float* node_feat = (const float*)d_in[0];
    const int*   edge_idx  = (const int*)  d_in[1];
    const float* edge_feat = (const float*)d_in[2];
    const float* W_np      = (const float*)d_in[3];
    const float* b_np      = (const float*)d_in[4];
    const float* W_e       = (const float*)d_in[5];
    const float* b_e       = (const float*)d_in[6];
    const float* W_ih      = (const float*)d_in[7];
    const float* W_hh      = (const float*)d_in[8];
    const float* b_ih      = (const float*)d_in[9];
    const float* b_hh      = (const float*)d_in[10];

    float* h      = (float*)d_ws;                             // N*H
    float* U      = h + (size_t)N_NODES * H;                  // N*UROW
    float* ef2    = U + (size_t)N_NODES * UROW;               // E*EDGE_DIM
    float* msg    = ef2 + (size_t)N_EDGES * EDGE_DIM;         // E*H (20.5 MB)
    int* rowptr   = (int*)(msg + (size_t)N_EDGES * H);        // N+1
    int* cursor   = rowptr + (N_NODES + 1);                   // N
    int* bsum     = cursor + N_NODES;                         // 80
    int* rowptr_d = bsum + 80;                                // N+1
    int* cursor_d = rowptr_d + (N_NODES + 1);                 // N
    int* bsum_d   = cursor_d + N_NODES;                       // 80
    int* eperm    = bsum_d + 80;                              // E
    int* src2     = eperm + N_EDGES;                          // E
    int* dst2     = src2 + N_EDGES;                           // E
    int* jslot    = dst2 + N_EDGES;                           // E
    float* out    = (float*)d_out;

    // ---- one-time: build src-sorted edge arrays + dst-CSR slot map ----
    hipMemsetAsync(cursor,   0, N_NODES * sizeof(int), stream);
    hipMemsetAsync(cursor_d, 0, N_NODES * sizeof(int), stream);
    hist_src_kernel<<<(N_EDGES + 255) / 256, 256, 0, stream>>>(edge_idx, cursor);
    hist_dst_kernel<<<(N_EDGES + 255) / 256, 256, 0, stream>>>(edge_idx, cursor_d);
    scan_a_kernel<<<(N_NODES + 255) / 256, 256, 0, stream>>>(cursor, rowptr, bsum);
    scan_b_kernel<<<1, 256, 0, stream>>>(rowptr, bsum, cursor);
    scan_a_kernel<<<(N_NODES + 255) / 256, 256, 0, stream>>>(cursor_d, rowptr_d, bsum_d);
    scan_b_kernel<<<1, 256, 0, stream>>>(rowptr_d, bsum_d, cursor_d);
    fill_src_kernel<<<(N_EDGES + 255) / 256, 256, 0, stream>>>(edge_idx, cursor,
                                                               eperm, src2, dst2);
    fill_dst_kernel<<<(N_EDGES + 255) / 256, 256, 0, stream>>>(dst2, cursor_d, jslot);
    permute_ef_kernel<<<(N_EDGES * EDGE_DIM + 255) / 256, 256, 0, stream>>>(
        edge_feat, eperm, ef2);

    // ---- h0 ----
    node_proj_kernel<<<(N_NODES * H + 255) / 256, 256, 0, stream>>>(
        node_feat, W_np, b_np, h);

    // ---- 3 propagation steps ----
    for (int step = 0; step < STEPS; ++step) {
        u_precompute_kernel<<<313, 576, 0, stream>>>(W_e, b_e, h, U);
        edge_msg_kernel<<<(N_EDGES * H + 255) / 256, 256, 0, stream>>>(
            src2, jslot, ef2, U, msg);
        float* dst_h = (step == STEPS - 1) ? out : h;
        gru_kernel<<<2500, 256, 0, stream>>>(W_ih, W_hh, b_ih, b_hh,
                                             msg, rowptr_d, h, dst_h);
    }
}

// Round 3
// 424.123 us; speedup vs baseline: 1.3343x; 1.1370x over previous
//
#include <hip/hip_runtime.h>
#include <math.h>

#define N_NODES 20000
#define N_EDGES 160000
#define NODE_DIM 64
#define EDGE_DIM 16
#define H 32
#define STEPS 3
#define UROW 544   // U[v][c]: c = i*16+d for c<512 (i=c>>4,d=c&15); c=512+i is bias plane

// ---------------------------------------------------------------------------
// CSR build (once per call), twice: by src (edge_msg U-row locality) and by
// dst (contiguous message rows for the GRU gather). hist -> 2-level scan ->
// atomic fill. The dst fill emits jslot[j] = dst-sorted slot for src-sorted
// edge j, so edge_msg SCATTER-WRITES (latency-tolerant) and the GRU reads
// CONTIGUOUS rows (no indirection, no pointer chase).
// ---------------------------------------------------------------------------
__global__ void hist_src_kernel(const int* __restrict__ ei, int* __restrict__ deg) {
    int e = blockIdx.x * 256 + threadIdx.x;
    if (e < N_EDGES) atomicAdd(&deg[ei[e]], 1);               // row 0 = src
}

__global__ void hist_dst_kernel(const int* __restrict__ ei, int* __restrict__ deg) {
    int e = blockIdx.x * 256 + threadIdx.x;
    if (e < N_EDGES) atomicAdd(&deg[ei[N_EDGES + e]], 1);     // row 1 = dst
}

__global__ void scan_a_kernel(const int* __restrict__ deg,
                              int* __restrict__ part, int* __restrict__ bsum) {
    __shared__ int s[256];
    int v = blockIdx.x * 256 + threadIdx.x;
    int x = (v < N_NODES) ? deg[v] : 0;
    s[threadIdx.x] = x;
    __syncthreads();
    for (int off = 1; off < 256; off <<= 1) {
        int t = (threadIdx.x >= off) ? s[threadIdx.x - off] : 0;
        __syncthreads();
        s[threadIdx.x] += t;
        __syncthreads();
    }
    if (v < N_NODES) part[v] = s[threadIdx.x] - x;
    if (threadIdx.x == 255) bsum[blockIdx.x] = s[255];
}

__global__ void scan_b_kernel(int* __restrict__ rowptr,
                              const int* __restrict__ bsum,
                              int* __restrict__ cursor) {
    __shared__ int boff[80];
    if (threadIdx.x == 0) {
        int run = 0;
        for (int b = 0; b < 79; ++b) { boff[b] = run; run += bsum[b]; }
    }
    __syncthreads();
    for (int v = threadIdx.x; v < N_NODES; v += 256) {
        int r = rowptr[v] + boff[v >> 8];
        rowptr[v] = r;
        cursor[v] = r;
    }
    if (threadIdx.x == 0) rowptr[N_NODES] = N_EDGES;
}

__global__ void fill_src_kernel(const int* __restrict__ ei, int* __restrict__ cursor,
                                int* __restrict__ eperm, int* __restrict__ src2,
                                int* __restrict__ dst2) {
    int e = blockIdx.x * 256 + threadIdx.x;
    if (e < N_EDGES) {
        int s = ei[e];
        int slot = atomicAdd(&cursor[s], 1);
        eperm[slot] = e;
        src2[slot]  = s;
        dst2[slot]  = ei[N_EDGES + e];
    }
}

// jslot[j] = position of src-sorted edge j within the dst-sorted ordering
__global__ void fill_dst_kernel(const int* __restrict__ dst2, int* __restrict__ cursor,
                                int* __restrict__ jslot) {
    int j = blockIdx.x * 256 + threadIdx.x;
    if (j < N_EDGES) {
        int slot = atomicAdd(&cursor[dst2[j]], 1);
        jslot[j] = slot;
    }
}

__global__ void permute_ef_kernel(const float* __restrict__ ef,
                                  const int* __restrict__ eperm,
                                  float* __restrict__ ef2) {
    int t = blockIdx.x * 256 + threadIdx.x;
    if (t < N_EDGES * EDGE_DIM) {
        int j = t >> 4;
        int d = t & 15;
        ef2[t] = ef[eperm[j] * EDGE_DIM + d];
    }
}

// ---------------------------------------------------------------------------
// node projection: h = node_feat @ W_np.T + b_np
// ---------------------------------------------------------------------------
__global__ void node_proj_kernel(const float* __restrict__ nf,
                                 const float* __restrict__ W,
                                 const float* __restrict__ b,
                                 float* __restrict__ h) {
    int tid = blockIdx.x * blockDim.x + threadIdx.x;
    if (tid >= N_NODES * H) return;
    int v = tid >> 5;
    int i = tid & 31;
    const float* __restrict__ row = nf + v * NODE_DIM;
    const float* __restrict__ w   = W + i * NODE_DIM;
    float acc = b[i];
#pragma unroll
    for (int d = 0; d < NODE_DIM; ++d) acc = fmaf(row[d], w[d], acc);
    h[tid] = acc;
}

// ---------------------------------------------------------------------------
// U precompute v3: U[v, c] = sum_k Wx[k][c] * h[v,k]
// where Wx[k][c] = We[((c>>4)*32+k)*16 + (c&15)]  (c < 512)
//                = be[(c-512)*32 + k]             (512 <= c < 544, bias plane)
// ---------------------------------------------------------------------------
__global__ __launch_bounds__(576)
void u_precompute_kernel(const float* __restrict__ We,
                         const float* __restrict__ be,
                         const float* __restrict__ h,
                         float* __restrict__ U) {
    __shared__ float hs[32 * 32];   // 4 KB
    int t = threadIdx.x;
    int c = t;

    float wreg[32];
    if (c < 512) {
        int i = c >> 4, d = c & 15;
#pragma unroll
        for (int k = 0; k < H; ++k) wreg[k] = We[(i * H + k) * EDGE_DIM + d];
    } else if (c < UROW) {
        int i = c - 512;
#pragma unroll
        for (int k = 0; k < H; ++k) wreg[k] = be[i * H + k];
    }

    for (int v0 = blockIdx.x * 32; v0 < N_NODES; v0 += gridDim.x * 32) {
        __syncthreads();
        for (int idx = t; idx < 32 * 32; idx += 576) hs[idx] = h[v0 * H + idx];
        __syncthreads();

        for (int n = 0; n < 32; n += 2) {
            const float4* __restrict__ hp0 = (const float4*)(hs + n * H);
            const float4* __restrict__ hp1 = (const float4*)(hs + (n + 1) * H);
            float a0 = 0.f, a1 = 0.f;
#pragma unroll
            for (int kk = 0; kk < 8; ++kk) {
                float4 q0 = hp0[kk];
                float4 q1 = hp1[kk];
                a0 = fmaf(wreg[4 * kk + 0], q0.x, a0);
                a1 = fmaf(wreg[4 * kk + 0], q1.x, a1);
                a0 = fmaf(wreg[4 * kk + 1], q0.y, a0);
                a1 = fmaf(wreg[4 * kk + 1], q1.y, a1);
                a0 = fmaf(wreg[4 * kk + 2], q0.z, a0);
                a1 = fmaf(wreg[4 * kk + 2], q1.z, a1);
                a0 = fmaf(wreg[4 * kk + 3], q0.w, a0);
                a1 = fmaf(wreg[4 * kk + 3], q1.w, a1);
            }
            if (c < UROW) {
                U[(size_t)(v0 + n)     * UROW + c] = a0;
                U[(size_t)(v0 + n + 1) * UROW + c] = a1;
            }
        }
    }
}

// ---------------------------------------------------------------------------
// Edge message (src-sorted read, dst-sorted SCATTER write — no atomics):
//   msg[jslot[j], i] = U[s,512+i] + sum_d ef2[j,d] * U[s, i*16+d]
// ---------------------------------------------------------------------------
__global__ __launch_bounds__(256)
void edge_msg_kernel(const int* __restrict__ src2,
                     const int* __restrict__ jslot,
                     const float* __restrict__ ef2,
                     const float* __restrict__ U,
                     float* __restrict__ msg_out) {
    int tid  = blockIdx.x * blockDim.x + threadIdx.x;
    int j    = tid >> 5;
    int lane = tid & 31;
    if (j >= N_EDGES) return;

    int s    = src2[j];
    int slot = jslot[j];

    float efv = (lane < EDGE_DIM) ? ef2[j * EDGE_DIM + lane] : 0.f;

    const float* __restrict__ Up = U + (size_t)s * UROW;
    const float4* __restrict__ Urow = (const float4*)(Up + lane * EDGE_DIM);
    float4 u0 = Urow[0];
    float4 u1 = Urow[1];
    float4 u2 = Urow[2];
    float4 u3 = Urow[3];

    float msg = Up[512 + lane];   // bias plane
    msg = fmaf(__shfl(efv,  0, 32), u0.x, msg);
    msg = fmaf(__shfl(efv,  1, 32), u0.y, msg);
    msg = fmaf(__shfl(efv,  2, 32), u0.z, msg);
    msg = fmaf(__shfl(efv,  3, 32), u0.w, msg);
    msg = fmaf(__shfl(efv,  4, 32), u1.x, msg);
    msg = fmaf(__shfl(efv,  5, 32), u1.y, msg);
    msg = fmaf(__shfl(efv,  6, 32), u1.z, msg);
    msg = fmaf(__shfl(efv,  7, 32), u1.w, msg);
    msg = fmaf(__shfl(efv,  8, 32), u2.x, msg);
    msg = fmaf(__shfl(efv,  9, 32), u2.y, msg);
    msg = fmaf(__shfl(efv, 10, 32), u2.z, msg);
    msg = fmaf(__shfl(efv, 11, 32), u2.w, msg);
    msg = fmaf(__shfl(efv, 12, 32), u3.x, msg);
    msg = fmaf(__shfl(efv, 13, 32), u3.y, msg);
    msg = fmaf(__shfl(efv, 14, 32), u3.z, msg);
    msg = fmaf(__shfl(efv, 15, 32), u3.w, msg);

    msg_out[(size_t)slot * H + lane] = msg;   // scatter to dst-sorted slot
}

// ---------------------------------------------------------------------------
// GRU v3: register-weight column-GEMM.
//   Columns c=0..127: [0,32)=r_sum, [32,64)=z_sum, [64,96)=in (m only),
//   [96,128)=hn (h only). Thread c holds its 64-weight column in 16 float4
//   VGPRs (zero-padded halves for n-gates). x=[m|h] staged in LDS, read as
//   same-address broadcast b128. Gate assembly via pad-5 LDS (conflict-free).
//   Kills the 256 LDS-ops/node-pair of the shfl version (~70 now).
// ---------------------------------------------------------------------------
__global__ __launch_bounds__(256, 4)
void gru_kernel(const float* __restrict__ Wih,
                const float* __restrict__ Whh,
                const float* __restrict__ bih,
                const float* __restrict__ bhh,
                const float* __restrict__ msg,
                const int* __restrict__ rowptr_d,
                const float* __restrict__ h,
                float* __restrict__ hout) {
    __shared__ float xs[16 * 64];        // [node][ m(32) | h(32) ]   4 KB
    __shared__ float gs[16 * 32 * 5];    // [node][i][gate + pad]    10 KB

    // ---- register-resident weight column for c = tid & 127 ----
    int c = threadIdx.x & 127;
    float4 wc[16];
    if (c < 96) {
        const float4* p = (const float4*)(Wih + c * H);
#pragma unroll
        for (int q = 0; q < 8; ++q) wc[q] = p[q];
    } else {
#pragma unroll
        for (int q = 0; q < 8; ++q) wc[q] = make_float4(0.f, 0.f, 0.f, 0.f);
    }
    int hrow = (c < 64) ? c : ((c >= 96) ? (c - 32) : -1);
    if (hrow >= 0) {
        const float4* p = (const float4*)(Whh + hrow * H);
#pragma unroll
        for (int q = 0; q < 8; ++q) wc[8 + q] = p[q];
    } else {
#pragma unroll
        for (int q = 0; q < 8; ++q) wc[8 + q] = make_float4(0.f, 0.f, 0.f, 0.f);
    }
    float bias;
    if (c < 64)      bias = bih[c] + bhh[c];      // r_sum / z_sum
    else if (c < 96) bias = bih[c];               // in
    else             bias = bhh[c - 32];          // hn

    int g    = threadIdx.x >> 5;    // gather group 0..7
    int lane = threadIdx.x & 31;
    int half = threadIdx.x >> 7;    // 0: nodes 0..7, 1: nodes 8..15
    int ci   = c & 31;
    int gt   = c >> 5;

    for (int v0 = blockIdx.x * 16; v0 < N_NODES; v0 += gridDim.x * 16) {
        // ---- phase A: contiguous msg gather + h stage ----
#pragma unroll
        for (int nn = 0; nn < 2; ++nn) {
            int n = g + nn * 8;
            int v = v0 + n;
            int beg = rowptr_d[v], end = rowptr_d[v + 1];
            float a0 = 0.f, a1 = 0.f;
            const float* mp = msg + (size_t)beg * H + lane;
            int p = beg;
            for (; p + 2 <= end; p += 2) { a0 += mp[0]; a1 += mp[H]; mp += 2 * H; }
            if (p < end) a0 += mp[0];
            xs[n * 64 + lane]      = a0 + a1;
            xs[n * 64 + 32 + lane] = h[(size_t)v * H + lane];
        }
        __syncthreads();

        // ---- phase B: column-GEMM, 2 nodes per pass for ILP ----
#pragma unroll
        for (int n = 0; n < 8; n += 2) {
            const float4* x0 = (const float4*)(xs + (half * 8 + n) * 64);
            const float4* x1 = (const float4*)(xs + (half * 8 + n + 1) * 64);
            float acc0 = bias, acc1 = bias;
#pragma unroll
            for (int q = 0; q < 16; ++q) {
                float4 w = wc[q];
                float4 a = x0[q];
                float4 b = x1[q];
                acc0 = fmaf(w.x, a.x, acc0); acc1 = fmaf(w.x, b.x, acc1);
                acc0 = fmaf(w.y, a.y, acc0); acc1 = fmaf(w.y, b.y, acc1);
                acc0 = fmaf(w.z, a.z, acc0); acc1 = fmaf(w.z, b.z, acc1);
                acc0 = fmaf(w.w, a.w, acc0); acc1 = fmaf(w.w, b.w, acc1);
            }
            gs[((half * 8 + n)     * 32 + ci) * 5 + gt] = acc0;
            gs[((half * 8 + n + 1) * 32 + ci) * 5 + gt] = acc1;
        }
        __syncthreads();

        // ---- phase C: gates + output ----
        for (int t = threadIdx.x; t < 16 * 32; t += 256) {
            int nl = t >> 5, ii = t & 31;
            const float* gp = gs + (size_t)t * 5;
            float rs = gp[0], zs = gp[1], in_ = gp[2], hn = gp[3];
            float hv = xs[nl * 64 + 32 + ii];
            float r   = 1.f / (1.f + __expf(-rs));
            float z   = 1.f / (1.f + __expf(-zs));
            float nn2 = tanhf(in_ + r * hn);
            hout[(size_t)(v0 + nl) * H + ii] = (1.f - z) * nn2 + z * hv;
        }
        __syncthreads();   // xs/gs reused next iteration
    }
}

// ---------------------------------------------------------------------------
extern "C" void kernel_launch(void* const* d_in, const int* in_sizes, int n_in,
                              void* d_out, int out_size, void* d_ws, size_t ws_size,
                              hipStream_t stream) {
    const float* node_feat = (const float*)d_in[0];
    const int*   edge_idx  = (const int*)  d_in[1];
    const float* edge_feat = (const float*)d_in[2];
    const float* W_np      = (const float*)d_in[3];
    const float* b_np      = (const float*)d_in[4];
    const float* W_e       = (const float*)d_in[5];
    const float* b_e       = (const float*)d_in[6];
    const float* W_ih      = (const float*)d_in[7];
    const float* W_hh      = (const float*)d_in[8];
    const float* b_ih      = (const float*)d_in[9];
    const float* b_hh      = (const float*)d_in[10];

    float* h      = (float*)d_ws;                             // N*H
    float* U      = h + (size_t)N_NODES * H;                  // N*UROW
    float* ef2    = U + (size_t)N_NODES * UROW;               // E*EDGE_DIM
    float* msg    = ef2 + (size_t)N_EDGES * EDGE_DIM;         // E*H (20.5 MB)
    int* rowptr   = (int*)(msg + (size_t)N_EDGES * H);        // N+1
    int* cursor   = rowptr + (N_NODES + 1);                   // N
    int* bsum     = cursor + N_NODES;                         // 80
    int* rowptr_d = bsum + 80;                                // N+1
    int* cursor_d = rowptr_d + (N_NODES + 1);                 // N
    int* bsum_d   = cursor_d + N_NODES;                       // 80
    int* eperm    = bsum_d + 80;                              // E
    int* src2     = eperm + N_EDGES;                          // E
    int* dst2     = src2 + N_EDGES;                           // E
    int* jslot    = dst2 + N_EDGES;                           // E
    float* out    = (float*)d_out;

    // ---- one-time: build src-sorted edge arrays + dst-CSR slot map ----
    hipMemsetAsync(cursor,   0, N_NODES * sizeof(int), stream);
    hipMemsetAsync(cursor_d, 0, N_NODES * sizeof(int), stream);
    hist_src_kernel<<<(N_EDGES + 255) / 256, 256, 0, stream>>>(edge_idx, cursor);
    hist_dst_kernel<<<(N_EDGES + 255) / 256, 256, 0, stream>>>(edge_idx, cursor_d);
    scan_a_kernel<<<(N_NODES + 255) / 256, 256, 0, stream>>>(cursor, rowptr, bsum);
    scan_b_kernel<<<1, 256, 0, stream>>>(rowptr, bsum, cursor);
    scan_a_kernel<<<(N_NODES + 255) / 256, 256, 0, stream>>>(cursor_d, rowptr_d, bsum_d);
    scan_b_kernel<<<1, 256, 0, stream>>>(rowptr_d, bsum_d, cursor_d);
    fill_src_kernel<<<(N_EDGES + 255) / 256, 256, 0, stream>>>(edge_idx, cursor,
                                                               eperm, src2, dst2);
    fill_dst_kernel<<<(N_EDGES + 255) / 256, 256, 0, stream>>>(dst2, cursor_d, jslot);
    permute_ef_kernel<<<(N_EDGES * EDGE_DIM + 255) / 256, 256, 0, stream>>>(
        edge_feat, eperm, ef2);

    // ---- h0 ----
    node_proj_kernel<<<(N_NODES * H + 255) / 256, 256, 0, stream>>>(
        node_feat, W_np, b_np, h);

    // ---- 3 propagation steps ----
    for (int step = 0; step < STEPS; ++step) {
        u_precompute_kernel<<<313, 576, 0, stream>>>(W_e, b_e, h, U);
        edge_msg_kernel<<<(N_EDGES * H + 255) / 256, 256, 0, stream>>>(
            src2, jslot, ef2, U, msg);
        float* dst_h = (step == STEPS - 1) ? out : h;
        gru_kernel<<<1250, 256, 0, stream>>>(W_ih, W_hh, b_ih, b_hh,
                                             msg, rowptr_d, h, dst_h);
    }
}

// Round 4
// 312.366 us; speedup vs baseline: 1.8116x; 1.3578x over previous
//
#include <hip/hip_runtime.h>
#include <math.h>

#define N_NODES 20000
#define N_EDGES 160000
#define NODE_DIM 64
#define EDGE_DIM 16
#define H 32
#define STEPS 3

// ---------------------------------------------------------------------------
// CSR-by-src build (once per call): hist -> 2-level scan -> atomic fill that
// emits src-sorted src2/dst2/eperm; ef permuted into ef2.
// ---------------------------------------------------------------------------
__global__ void hist_src_kernel(const int* __restrict__ ei, int* __restrict__ deg) {
    int e = blockIdx.x * 256 + threadIdx.x;
    if (e < N_EDGES) atomicAdd(&deg[ei[e]], 1);               // row 0 = src
}

__global__ void scan_a_kernel(const int* __restrict__ deg,
                              int* __restrict__ part, int* __restrict__ bsum) {
    __shared__ int s[256];
    int v = blockIdx.x * 256 + threadIdx.x;
    int x = (v < N_NODES) ? deg[v] : 0;
    s[threadIdx.x] = x;
    __syncthreads();
    for (int off = 1; off < 256; off <<= 1) {
        int t = (threadIdx.x >= off) ? s[threadIdx.x - off] : 0;
        __syncthreads();
        s[threadIdx.x] += t;
        __syncthreads();
    }
    if (v < N_NODES) part[v] = s[threadIdx.x] - x;
    if (threadIdx.x == 255) bsum[blockIdx.x] = s[255];
}

__global__ void scan_b_kernel(int* __restrict__ rowptr,
                              const int* __restrict__ bsum,
                              int* __restrict__ cursor) {
    __shared__ int boff[80];
    if (threadIdx.x == 0) {
        int run = 0;
        for (int b = 0; b < 79; ++b) { boff[b] = run; run += bsum[b]; }
    }
    __syncthreads();
    for (int v = threadIdx.x; v < N_NODES; v += 256) {
        int r = rowptr[v] + boff[v >> 8];
        rowptr[v] = r;
        cursor[v] = r;
    }
    if (threadIdx.x == 0) rowptr[N_NODES] = N_EDGES;
}

__global__ void fill_src_kernel(const int* __restrict__ ei, int* __restrict__ cursor,
                                int* __restrict__ eperm, int* __restrict__ src2,
                                int* __restrict__ dst2) {
    int e = blockIdx.x * 256 + threadIdx.x;
    if (e < N_EDGES) {
        int s = ei[e];
        int slot = atomicAdd(&cursor[s], 1);
        eperm[slot] = e;
        src2[slot]  = s;
        dst2[slot]  = ei[N_EDGES + e];
    }
}

__global__ void permute_ef_kernel(const float* __restrict__ ef,
                                  const int* __restrict__ eperm,
                                  float* __restrict__ ef2) {
    int t = blockIdx.x * 256 + threadIdx.x;
    if (t < N_EDGES * EDGE_DIM) {
        int j = t >> 4;
        int d = t & 15;
        ef2[t] = ef[eperm[j] * EDGE_DIM + d];
    }
}

// ---------------------------------------------------------------------------
// node projection: h = node_feat @ W_np.T + b_np
// ---------------------------------------------------------------------------
__global__ void node_proj_kernel(const float* __restrict__ nf,
                                 const float* __restrict__ W,
                                 const float* __restrict__ b,
                                 float* __restrict__ h) {
    int tid = blockIdx.x * blockDim.x + threadIdx.x;
    if (tid >= N_NODES * H) return;
    int v = tid >> 5;
    int i = tid & 31;
    const float* __restrict__ row = nf + v * NODE_DIM;
    const float* __restrict__ w   = W + i * NODE_DIM;
    float acc = b[i];
#pragma unroll
    for (int d = 0; d < NODE_DIM; ++d) acc = fmaf(row[d], w[d], acc);
    h[tid] = acc;
}

// ---------------------------------------------------------------------------
// FUSED U-precompute + edge message (U lives only in LDS, never HBM).
//   Block owns 16 src nodes; src-sorted CSR makes its edges one contiguous
//   range rowptr[v0]..rowptr[v0+16].
//   Phase 1: U[ls, c] = sum_k Wx[k][c] * h[v0+ls, k] into LDS.
//     Swizzled row layout (stride 576 floats): col c<512 with L=c>>4,
//     q=(c>>2)&3, e=c&3 stored at p = q*136 + L*4 + e; bias col 512+i at
//     544+i. Write banks <=2-way; edge-phase read = ds_read_b128 at
//     lane-stride 16B (ideal conflict-free pattern).
//   Phase 2: per edge j (one per half-wave):
//     msg[i] = U[ls,512+i] + sum_d ef2[j,d]*U[ls, i*16+d];
//     atomicAdd(&m[dst*H+i], msg)  -- fire-and-forget scatter.
// ---------------------------------------------------------------------------
__global__ __launch_bounds__(576)
void fused_msg_kernel(const float* __restrict__ We,
                      const float* __restrict__ be,
                      const float* __restrict__ h,
                      const int* __restrict__ rowptr,
                      const int* __restrict__ src2,
                      const int* __restrict__ dst2,
                      const float* __restrict__ ef2,
                      float* __restrict__ m) {
    __shared__ float hs[16 * 32];     // 2 KB
    __shared__ float Ul[16 * 576];    // 36 KB (swizzled, 576-float row stride)

    int t = threadIdx.x;

    // ---- per-thread weight column (registers) ----
    float wreg[32];
    int p = -1;
    if (t < 512) {
        int L = t >> 4, q = (t >> 2) & 3, e = t & 3;
        int d = t & 15;
#pragma unroll
        for (int k = 0; k < H; ++k) wreg[k] = We[(L * H + k) * EDGE_DIM + d];
        p = q * 136 + L * 4 + e;
    } else if (t < 544) {
        int i = t - 512;
#pragma unroll
        for (int k = 0; k < H; ++k) wreg[k] = be[i * H + k];
        p = 544 + i;
    }

    int v0 = blockIdx.x * 16;

    // ---- stage h rows ----
    if (t < 512) hs[t] = h[(size_t)v0 * H + t];
    __syncthreads();

    // ---- U compute into LDS (2 nodes per pass, broadcast f4 reads) ----
    if (p >= 0) {
        for (int n = 0; n < 16; n += 2) {
            const float4* __restrict__ hp0 = (const float4*)(hs + n * H);
            const float4* __restrict__ hp1 = (const float4*)(hs + (n + 1) * H);
            float a0 = 0.f, a1 = 0.f;
#pragma unroll
            for (int kk = 0; kk < 8; ++kk) {
                float4 q0 = hp0[kk];
                float4 q1 = hp1[kk];
                a0 = fmaf(wreg[4 * kk + 0], q0.x, a0);
                a1 = fmaf(wreg[4 * kk + 0], q1.x, a1);
                a0 = fmaf(wreg[4 * kk + 1], q0.y, a0);
                a1 = fmaf(wreg[4 * kk + 1], q1.y, a1);
                a0 = fmaf(wreg[4 * kk + 2], q0.z, a0);
                a1 = fmaf(wreg[4 * kk + 2], q1.z, a1);
                a0 = fmaf(wreg[4 * kk + 3], q0.w, a0);
                a1 = fmaf(wreg[4 * kk + 3], q1.w, a1);
            }
            Ul[n * 576 + p]       = a0;
            Ul[(n + 1) * 576 + p] = a1;
        }
    }
    __syncthreads();

    // ---- edge phase: one edge per half-wave, U from LDS ----
    int hw   = t >> 5;          // 0..17
    int lane = t & 31;
    int jbeg = rowptr[v0];
    int jend = rowptr[v0 + 16];
    for (int j = jbeg + hw; j < jend; j += 18) {
        int s  = src2[j];
        int ls = s - v0;
        int dd = dst2[j];

        float efv = (lane < EDGE_DIM) ? ef2[(size_t)j * EDGE_DIM + lane] : 0.f;

        const float*  __restrict__ Ur = Ul + ls * 576;
        const float4* __restrict__ up = (const float4*)Ur;
        float4 u0 = up[0 * 34 + lane];   // cols lane*16 + 0..3
        float4 u1 = up[1 * 34 + lane];   // cols lane*16 + 4..7
        float4 u2 = up[2 * 34 + lane];   // cols lane*16 + 8..11
        float4 u3 = up[3 * 34 + lane];   // cols lane*16 + 12..15
        float msg = Ur[544 + lane];      // bias plane

        msg = fmaf(__shfl(efv,  0, 32), u0.x, msg);
        msg = fmaf(__shfl(efv,  1, 32), u0.y, msg);
        msg = fmaf(__shfl(efv,  2, 32), u0.z, msg);
        msg = fmaf(__shfl(efv,  3, 32), u0.w, msg);
        msg = fmaf(__shfl(efv,  4, 32), u1.x, msg);
        msg = fmaf(__shfl(efv,  5, 32), u1.y, msg);
        msg = fmaf(__shfl(efv,  6, 32), u1.z, msg);
        msg = fmaf(__shfl(efv,  7, 32), u1.w, msg);
        msg = fmaf(__shfl(efv,  8, 32), u2.x, msg);
        msg = fmaf(__shfl(efv,  9, 32), u2.y, msg);
        msg = fmaf(__shfl(efv, 10, 32), u2.z, msg);
        msg = fmaf(__shfl(efv, 11, 32), u2.w, msg);
        msg = fmaf(__shfl(efv, 12, 32), u3.x, msg);
        msg = fmaf(__shfl(efv, 13, 32), u3.y, msg);
        msg = fmaf(__shfl(efv, 14, 32), u3.z, msg);
        msg = fmaf(__shfl(efv, 15, 32), u3.w, msg);

        atomicAdd(&m[(size_t)dd * H + lane], msg);
    }
}

// ---------------------------------------------------------------------------
// GRU v3 (register-weight column-GEMM), reading m directly + self-zeroing it
// for the next step's atomics.
// ---------------------------------------------------------------------------
__global__ __launch_bounds__(256, 4)
void gru_kernel(const float* __restrict__ Wih,
                const float* __restrict__ Whh,
                const float* __restrict__ bih,
                const float* __restrict__ bhh,
                float* __restrict__ m,
                const float* __restrict__ h,
                float* __restrict__ hout) {
    __shared__ float xs[16 * 64];        // [node][ m(32) | h(32) ]   4 KB
    __shared__ float gs[16 * 32 * 5];    // [node][i][gate + pad]    10 KB

    // ---- register-resident weight column for c = tid & 127 ----
    int c = threadIdx.x & 127;
    float4 wc[16];
    if (c < 96) {
        const float4* p = (const float4*)(Wih + c * H);
#pragma unroll
        for (int q = 0; q < 8; ++q) wc[q] = p[q];
    } else {
#pragma unroll
        for (int q = 0; q < 8; ++q) wc[q] = make_float4(0.f, 0.f, 0.f, 0.f);
    }
    int hrow = (c < 64) ? c : ((c >= 96) ? (c - 32) : -1);
    if (hrow >= 0) {
        const float4* p = (const float4*)(Whh + hrow * H);
#pragma unroll
        for (int q = 0; q < 8; ++q) wc[8 + q] = p[q];
    } else {
#pragma unroll
        for (int q = 0; q < 8; ++q) wc[8 + q] = make_float4(0.f, 0.f, 0.f, 0.f);
    }
    float bias;
    if (c < 64)      bias = bih[c] + bhh[c];      // r_sum / z_sum
    else if (c < 96) bias = bih[c];               // in
    else             bias = bhh[c - 32];          // hn

    int g    = threadIdx.x >> 5;    // node group 0..7
    int lane = threadIdx.x & 31;
    int half = threadIdx.x >> 7;    // 0: nodes 0..7, 1: nodes 8..15
    int ci   = c & 31;
    int gt   = c >> 5;

    int v0 = blockIdx.x * 16;
    {
        // ---- phase A: read m (and zero it), stage h ----
#pragma unroll
        for (int nn = 0; nn < 2; ++nn) {
            int n = g + nn * 8;
            int v = v0 + n;
            float mv = m[(size_t)v * H + lane];
            m[(size_t)v * H + lane] = 0.f;       // pre-zero for next step
            xs[n * 64 + lane]      = mv;
            xs[n * 64 + 32 + lane] = h[(size_t)v * H + lane];
        }
        __syncthreads();

        // ---- phase B: column-GEMM, 2 nodes per pass for ILP ----
#pragma unroll
        for (int n = 0; n < 8; n += 2) {
            const float4* x0 = (const float4*)(xs + (half * 8 + n) * 64);
            const float4* x1 = (const float4*)(xs + (half * 8 + n + 1) * 64);
            float acc0 = bias, acc1 = bias;
#pragma unroll
            for (int q = 0; q < 16; ++q) {
                float4 w = wc[q];
                float4 a = x0[q];
                float4 b = x1[q];
                acc0 = fmaf(w.x, a.x, acc0); acc1 = fmaf(w.x, b.x, acc1);
                acc0 = fmaf(w.y, a.y, acc0); acc1 = fmaf(w.y, b.y, acc1);
                acc0 = fmaf(w.z, a.z, acc0); acc1 = fmaf(w.z, b.z, acc1);
                acc0 = fmaf(w.w, a.w, acc0); acc1 = fmaf(w.w, b.w, acc1);
            }
            gs[((half * 8 + n)     * 32 + ci) * 5 + gt] = acc0;
            gs[((half * 8 + n + 1) * 32 + ci) * 5 + gt] = acc1;
        }
        __syncthreads();

        // ---- phase C: gates + output ----
        for (int t = threadIdx.x; t < 16 * 32; t += 256) {
            int nl = t >> 5, ii = t & 31;
            const float* gp = gs + (size_t)t * 5;
            float rs = gp[0], zs = gp[1], in_ = gp[2], hn = gp[3];
            float hv = xs[nl * 64 + 32 + ii];
            float r   = 1.f / (1.f + __expf(-rs));
            float z   = 1.f / (1.f + __expf(-zs));
            float nn2 = tanhf(in_ + r * hn);
            hout[(size_t)(v0 + nl) * H + ii] = (1.f - z) * nn2 + z * hv;
        }
    }
}

// ---------------------------------------------------------------------------
extern "C" void kernel_launch(void* const* d_in, const int* in_sizes, int n_in,
                              void* d_out, int out_size, void* d_ws, size_t ws_size,
                              hipStream_t stream) {
    const float* node_feat = (const float*)d_in[0];
    const int*   edge_idx  = (const int*)  d_in[1];
    const float* edge_feat = (const float*)d_in[2];
    const float* W_np      = (const float*)d_in[3];
    const float* b_np      = (const float*)d_in[4];
    const float* W_e       = (const float*)d_in[5];
    const float* b_e       = (const float*)d_in[6];
    const float* W_ih      = (const float*)d_in[7];
    const float* W_hh      = (const float*)d_in[8];
    const float* b_ih      = (const float*)d_in[9];
    const float* b_hh      = (const float*)d_in[10];

    float* h      = (float*)d_ws;                             // N*H
    float* m      = h + (size_t)N_NODES * H;                  // N*H
    float* ef2    = m + (size_t)N_NODES * H;                  // E*EDGE_DIM
    int* rowptr   = (int*)(ef2 + (size_t)N_EDGES * EDGE_DIM); // N+1
    int* cursor   = rowptr + (N_NODES + 1);                   // N
    int* bsum     = cursor + N_NODES;                         // 80
    int* eperm    = bsum + 80;                                // E
    int* src2     = eperm + N_EDGES;                          // E
    int* dst2     = src2 + N_EDGES;                           // E
    float* out    = (float*)d_out;

    // ---- one-time: zero m, build src-sorted CSR, permute ef ----
    hipMemsetAsync(m, 0, (size_t)N_NODES * H * sizeof(float), stream);
    hipMemsetAsync(cursor, 0, N_NODES * sizeof(int), stream);
    hist_src_kernel<<<(N_EDGES + 255) / 256, 256, 0, stream>>>(edge_idx, cursor);
    scan_a_kernel<<<(N_NODES + 255) / 256, 256, 0, stream>>>(cursor, rowptr, bsum);
    scan_b_kernel<<<1, 256, 0, stream>>>(rowptr, bsum, cursor);
    fill_src_kernel<<<(N_EDGES + 255) / 256, 256, 0, stream>>>(edge_idx, cursor,
                                                               eperm, src2, dst2);
    permute_ef_kernel<<<(N_EDGES * EDGE_DIM + 255) / 256, 256, 0, stream>>>(
        edge_feat, eperm, ef2);

    // ---- h0 ----
    node_proj_kernel<<<(N_NODES * H + 255) / 256, 256, 0, stream>>>(
        node_feat, W_np, b_np, h);

    // ---- 3 propagation steps (2 dispatches each) ----
    for (int step = 0; step < STEPS; ++step) {
        fused_msg_kernel<<<N_NODES / 16, 576, 0, stream>>>(
            W_e, b_e, h, rowptr, src2, dst2, ef2, m);
        float* dst_h = (step == STEPS - 1) ? out : h;
        gru_kernel<<<N_NODES / 16, 256, 0, stream>>>(W_ih, W_hh, b_ih, b_hh,
                                                     m, h, dst_h);
    }
}